// Round 3
// baseline (729.836 us; speedup 1.0000x reference)
//
#include <hip/hip_runtime.h>
#include <hip/hip_bf16.h>

typedef float f32x4 __attribute__((ext_vector_type(4)));
typedef int   i32x4 __attribute__((ext_vector_type(4)));

#define DELTA 5e-5f
#define LIST_CAP 4194304

// ---------------- weight prep: fold BN, per-cout i8 digit decomposition -------
// S = max_k |w*inv| / 127 (rounded to f32). d0=rint(w/S); d1=rint(254r/S);
// d2=rint(64516 r/S) (conv1 only). Layout per conv per split: [kc][cout][kk],
// k=r*128+cin, kc=k>>6, kk=k&63; split stride 147456 B; conv2 at +442368.
__global__ void prep_kernel(const float* __restrict__ w1, const float* __restrict__ g1,
                            const float* __restrict__ b1, const float* __restrict__ m1,
                            const float* __restrict__ v1,
                            const float* __restrict__ w2, const float* __restrict__ g2,
                            const float* __restrict__ b2, const float* __restrict__ m2,
                            const float* __restrict__ v2,
                            signed char* __restrict__ wp, float* __restrict__ off,
                            float* __restrict__ scl, int* __restrict__ cnt)
{
    __shared__ double red[128];
    const int blk  = blockIdx.x;       // 256 blocks = conv*128 + cout
    const int conv = blk >> 7;
    const int cout = blk & 127;
    const int cin  = threadIdx.x;      // 128 threads
    const float* w  = conv ? w2 : w1;
    const float* g  = conv ? g2 : g1;
    const float* bb = conv ? b2 : b1;
    const float* mm = conv ? m2 : m1;
    const float* vr = conv ? v2 : v1;
    const float invf = g[cout] / sqrtf(vr[cout] + 1e-5f);
    double wv[9];
    double mx = 0.0;
#pragma unroll
    for (int r = 0; r < 9; ++r) {
        wv[r] = (double)w[(size_t)(cout * 128 + cin) * 9 + r] * (double)invf;
        mx = fmax(mx, fabs(wv[r]));
    }
    red[cin] = mx;
    __syncthreads();
    for (int s = 64; s > 0; s >>= 1) {
        if (cin < s) red[cin] = fmax(red[cin], red[cin + s]);
        __syncthreads();
    }
    double S = red[0];
    S = (S > 0.0) ? (double)(float)(S / 127.0) : 1.0;
    const size_t base = conv ? (size_t)442368 : (size_t)0;
#pragma unroll
    for (int r = 0; r < 9; ++r) {
        double x = wv[r];
        const int k = r * 128 + cin;
        const size_t pos = ((size_t)(k >> 6) * 128 + cout) * 64 + (k & 63);
        int d0 = (int)rint(x / S);          x -= (double)d0 * S;
        int d1 = (int)rint(x * 254.0 / S);  x -= (double)d1 * S / 254.0;
        wp[base + pos]          = (signed char)d0;
        wp[base + 147456 + pos] = (signed char)d1;
        if (conv == 0) {
            int d2 = (int)rint(x * 64516.0 / S);
            wp[base + 294912 + pos] = (signed char)d2;
        }
    }
    if (cin == 0) {
        scl[conv * 128 + cout] = (float)S;
        off[conv * 128 + cout] = bb[cout] - mm[cout] * invf;
        if (blk == 0) cnt[0] = 0;          // ws re-poisoned every launch
    }
}

// ---------------- IF neuron #1: x [T,B,C,H,W] f32 -> spikes NHWC i8 -----------
// fp64 membrane: bit-matches an fp64 reference's spike decisions.
__global__ void if1_kernel(const float* __restrict__ x, signed char* __restrict__ s1)
{
    const int blk = blockIdx.x;        // 1024 = B*H
    const int b   = blk >> 5;
    const int h   = blk & 31;
    const int tid = threadIdx.x;
    const int w   = tid & 31;
    const int g   = tid >> 5;          // 8 groups of 16 channels
    double v[16];
#pragma unroll
    for (int i = 0; i < 16; ++i) v[i] = 0.0;
    for (int t = 0; t < 8; ++t) {
        const size_t xbase = ((((size_t)t * 32 + b) * 128 + g * 16) * 32 + h) * 32 + w;
        unsigned wds[4] = {0u, 0u, 0u, 0u};
#pragma unroll
        for (int i = 0; i < 16; ++i) {
            v[i] += (double)x[xbase + (size_t)i * 1024];
            const bool s = (v[i] >= 1.0);
            if (s) { wds[i >> 2] |= 1u << (8 * (i & 3)); v[i] = 0.0; }
        }
        int4 pk; pk.x = wds[0]; pk.y = wds[1]; pk.z = wds[2]; pk.w = wds[3];
        *(int4*)(s1 + (((size_t)(t * 32 + b) * 1024 + h * 32 + w) * 128 + g * 16)) = pk;
    }
}

// ---------------- conv1 (+folded BN) fused with IF#2 --------------------------
// Block = (b, 4-row strip, cout-half): grid 512, 2 blocks/CU. t-loop inside:
// membrane v[pixel][cout] lives in registers across t (each thread owns the
// same 32 sites every t). Per t: stage strip of s1[t] into LDS (loads issued
// BEFORE the MFMA loop of the previous tile -> HBM latency hidden), 18-kc i8
// MFMA loop with distance-2 wrap-around B prefetch (ring stays primed across
// t since weights are t-invariant), then f32 membrane update + spike + DELTA
// flag (identical decision arithmetic to the old if2_kernel; digit-combine
// error ~1e-7 << DELTA so flagged fp64 redo covers all borderline sites).
__global__ __launch_bounds__(256, 2)
void conv1_if2_kernel(const signed char* __restrict__ sin,
                      const signed char* __restrict__ wp,
                      const float* __restrict__ off, const float* __restrict__ scl,
                      signed char* __restrict__ s2,
                      int* __restrict__ cnt, int* __restrict__ list)
{
    __shared__ signed char img[6 * 34 * 128];   // 26,112 B
    const int tid  = threadIdx.x;
    const int blk  = blockIdx.x;       // 512 = b*16 + pblk*2 + ch
    const int b    = blk >> 4;
    const int pblk = (blk >> 1) & 7;
    const int ch   = blk & 1;
    const int wn = tid >> 6;
    const int lane15 = tid & 15;
    const int q  = (tid >> 4) & 3;
    const int cb = ch * 64 + wn * 16;
    const int y0 = pblk << 2;

    // staging slot decomposition (t-invariant): 1632 units = 204 px x 8 chunks
    int sdst[7], sga[7];
#pragma unroll
    for (int k = 0; k < 7; ++k) {
        const int unit = tid + k * 256;
        const int sp = unit >> 3, G = unit & 7;
        const int row = sp / 34, col = sp - row * 34;
        const int y = y0 + row - 1, xg = col - 1;
        sdst[k] = (unit < 1632) ? (sp * 128 + ((G ^ (col & 7)) * 16)) : -1;
        sga[k]  = (unit < 1632 && y >= 0 && y < 32 && xg >= 0 && xg < 32)
                  ? ((y * 32 + xg) * 128 + G * 16) : -1;
    }

    const float offv = off[cb + lane15];
    const float svf  = scl[cb + lane15];

    // prologue: stage t=0
    {
        const signed char* base = sin + (size_t)b * 131072;
#pragma unroll
        for (int k = 0; k < 7; ++k) {
            if (sdst[k] >= 0) {
                int4 r; r.x = r.y = r.z = r.w = 0;
                if (sga[k] >= 0) r = *(const int4*)(base + sga[k]);
                *(int4*)&img[sdst[k]] = r;
            }
        }
        __syncthreads();
    }

    const signed char* wbase = wp + ((size_t)(cb + lane15) * 64 + q * 16);
#define BLOAD1(s, kc) (*(const i32x4*)(wbase + (size_t)((s) * 18 + (kc)) * 8192))

    i32x4 buf[2][3];
#pragma unroll
    for (int s = 0; s < 3; ++s) { buf[0][s] = BLOAD1(s, 0); buf[1][s] = BLOAD1(s, 1); }

    float v[8][4];
#pragma unroll
    for (int i = 0; i < 8; ++i)
#pragma unroll
        for (int rg = 0; rg < 4; ++rg) v[i][rg] = 0.f;
    unsigned fmask = 0;

    for (int t = 0; t < 8; ++t) {
        // issue next-t staging loads early (latency hidden under MFMA loop)
        int4 r[7];
        if (t < 7) {
            const signed char* base = sin + (size_t)((t + 1) * 32 + b) * 131072;
#pragma unroll
            for (int k = 0; k < 7; ++k) {
                r[k].x = r[k].y = r[k].z = r[k].w = 0;
                if (sga[k] >= 0) r[k] = *(const int4*)(base + sga[k]);
            }
        }

        i32x4 acc[8][3];
#pragma unroll
        for (int i = 0; i < 8; ++i)
#pragma unroll
            for (int s = 0; s < 3; ++s)
#pragma unroll
                for (int rg = 0; rg < 4; ++rg) acc[i][s][rg] = 0;

        for (int tap = 0; tap < 9; ++tap) {
            const int dy = tap / 3 - 1;
            const int dx = tap - (tap / 3) * 3 - 1;
#pragma unroll
            for (int ci = 0; ci < 2; ++ci) {
                const int kc = tap * 2 + ci;
#pragma unroll
                for (int ih = 0; ih < 2; ++ih) {
                    i32x4 af[4];
#pragma unroll
                    for (int i4 = 0; i4 < 4; ++i4) {
                        const int i = ih * 4 + i4;
                        const int col = (i & 1) * 16 + lane15 + 1 + dx;
                        const int sp  = ((i >> 1) + 1 + dy) * 34 + col;
                        const int g   = (ci * 4 + q) ^ (col & 7);
                        af[i4] = *(const i32x4*)&img[sp * 128 + g * 16];
                    }
#pragma unroll
                    for (int s = 0; s < 3; ++s)
#pragma unroll
                        for (int i4 = 0; i4 < 4; ++i4)
                            acc[ih * 4 + i4][s] = __builtin_amdgcn_mfma_i32_16x16x64_i8(
                                af[i4], buf[kc & 1][s], acc[ih * 4 + i4][s], 0, 0, 0);
                }
                // distance-2 prefetch, wrap mod 18: ring is primed for next t
                const int kcn = (kc + 2 < 18) ? kc + 2 : kc - 16;
#pragma unroll
                for (int s = 0; s < 3; ++s) buf[kc & 1][s] = BLOAD1(s, kcn);
            }
        }

        // membrane + spike + near-threshold flag + s2 store (C/D: col=lane&15,
        // row=quad*4+reg). Same f32 decision stream as the old if2_kernel.
        const size_t obase = ((size_t)(t * 32 + b) * 1024) * 128;
#pragma unroll
        for (int i = 0; i < 8; ++i) {
            const int prow = pblk * 128 + i * 16 + q * 4;
#pragma unroll
            for (int rg = 0; rg < 4; ++rg) {
                const float y = fmaf((float)acc[i][0][rg]
                               + (float)acc[i][1][rg] * (1.0f / 254.0f)
                               + (float)acc[i][2][rg] * (1.0f / 64516.0f), svf, offv);
                v[i][rg] += y;
                const float d = v[i][rg] - 1.0f;
                if (fabsf(d) < DELTA) fmask |= 1u << (i * 4 + rg);
                const bool spk = (d >= 0.0f);
                s2[obase + (size_t)(prow + rg) * 128 + cb + lane15] = spk ? 1 : 0;
                if (spk) v[i][rg] = 0.f;
            }
        }

        if (t < 7) {
            __syncthreads();                    // all waves done reading img[t]
#pragma unroll
            for (int k = 0; k < 7; ++k)
                if (sdst[k] >= 0) *(int4*)&img[sdst[k]] = r[k];
            __syncthreads();                    // img[t+1] ready
        }
    }
#undef BLOAD1

    if (fmask) {
#pragma unroll 1
        for (int k = 0; k < 32; ++k)
            if ((fmask >> k) & 1) {
                const int i = k >> 2, rg = k & 3;
                const int p = pblk * 128 + i * 16 + q * 4 + rg;
                const int pos = atomicAdd(cnt, 1);
                if (pos < LIST_CAP)
                    list[pos] = (b << 17) | (p << 7) | (cb + lane15);
            }
    }
}

// ---------------- IF#2 phase B: fp64 redo from stored s1 spikes ---------------
// s1 holds if1's exact fp64 spike decisions; reading it (cin-contiguous 128-B
// rows) replaces the old 4KB-strided x gather (~64x less HBM touched/site).
__global__ __launch_bounds__(256)
void redo_kernel(const signed char* __restrict__ s1, const float* __restrict__ w1,
                 const float* __restrict__ g1, const float* __restrict__ b1,
                 const float* __restrict__ m1, const float* __restrict__ v1r,
                 const int* __restrict__ cnt, const int* __restrict__ list,
                 signed char* __restrict__ s2)
{
    __shared__ double red[256][8];   // 16 KB
    const int count = min(cnt[0], LIST_CAP);
    const int tid = threadIdx.x;
    const int cin = tid & 127;
    const int tg  = tid >> 7;
    for (int i = blockIdx.x; i < count; i += gridDim.x) {
        const int pk = list[i];
        const int b = pk >> 17, p = (pk >> 7) & 1023, c = pk & 127;
        const int h = p >> 5, w_ = p & 31;
        double part[8];
#pragma unroll
        for (int t = 0; t < 8; ++t) part[t] = 0.0;
        const int tap0 = tg ? 5 : 0, tap1 = tg ? 9 : 5;
        for (int tap = tap0; tap < tap1; ++tap) {
            const int hh = h + tap / 3 - 1;
            const int ww = w_ + tap - (tap / 3) * 3 - 1;
            if (hh < 0 || hh > 31 || ww < 0 || ww > 31) continue;
            const int pix = hh * 32 + ww;
            const double wv = (double)w1[(size_t)(c * 128 + cin) * 9 + tap];
#pragma unroll
            for (int t = 0; t < 8; ++t)
                if (s1[((size_t)(t * 32 + b) * 1024 + pix) * 128 + cin]) part[t] += wv;
        }
#pragma unroll
        for (int t = 0; t < 8; ++t) red[tid][t] = part[t];
        __syncthreads();
        for (int s = 128; s > 0; s >>= 1) {
            if (tid < s)
#pragma unroll
                for (int t = 0; t < 8; ++t) red[tid][t] += red[tid + s][t];
            __syncthreads();
        }
        if (tid == 0) {
            const double inv  = (double)g1[c] / sqrt((double)v1r[c] + 1e-5);
            const double offc = (double)b1[c] - (double)m1[c] * inv;
            double v = 0.0;
#pragma unroll
            for (int t = 0; t < 8; ++t) {
                v += red[0][t] * inv + offc;
                const bool s = (v >= 1.0);
                s2[((size_t)(t * 32 + b) * 1024 + p) * 128 + c] = s ? 1 : 0;
                if (s) v = 0.0;
            }
        }
        __syncthreads();   // LDS reused next site
    }
}

// ---------------- conv2 (+folded BN) on the i8 matrix pipe, NCHW out ----------
// 128 couts/block (full 512-B output lines: no write amplification); 2-digit
// exact i32 accumulation; distance-2 wrap B prefetch.
__global__ __launch_bounds__(256, 2)
void conv2_kernel(const signed char* __restrict__ sin, const signed char* __restrict__ wp,
                  const float* __restrict__ off, const float* __restrict__ scl,
                  float* __restrict__ out)
{
    __shared__ signed char img[6 * 34 * 128];   // 26,112 B
    const int tid  = threadIdx.x;
    const int blk  = blockIdx.x;     // 2048 = tb*8 + pblk
    const int tb   = blk >> 3;
    const int pblk = blk & 7;
    const int wn = tid >> 6;
    const int lane15 = tid & 15;
    const int q  = (tid >> 4) & 3;
    const int cb = wn * 32;
    const int y0 = pblk << 2;

    for (int unit = tid; unit < 1632; unit += 256) {
        const int sp = unit >> 3, G = unit & 7;
        const int row = sp / 34, col = sp - row * 34;
        const int y = y0 + row - 1, xg = col - 1;
        int4 vld; vld.x = vld.y = vld.z = vld.w = 0;
        if (y >= 0 && y < 32 && xg >= 0 && xg < 32)
            vld = *(const int4*)(sin + (((size_t)tb * 1024 + y * 32 + xg) * 128 + G * 16));
        *(int4*)&img[sp * 128 + ((G ^ (col & 7)) * 16)] = vld;
    }
    __syncthreads();

    i32x4 acc[8][2][2];   // [i][j][split]
#pragma unroll
    for (int i = 0; i < 8; ++i)
#pragma unroll
        for (int j = 0; j < 2; ++j)
#pragma unroll
            for (int s = 0; s < 2; ++s)
#pragma unroll
                for (int rg = 0; rg < 4; ++rg) acc[i][j][s][rg] = 0;

    const signed char* wbase = wp + ((size_t)(cb + lane15) * 64 + q * 16);
#define BLOAD2(s, j, kc) (*(const i32x4*)(wbase + ((size_t)((s) * 18 + (kc)) * 128 + (j) * 16) * 64))

    i32x4 buf[2][2][2];   // [ring][split][j]
#pragma unroll
    for (int s = 0; s < 2; ++s)
#pragma unroll
        for (int j = 0; j < 2; ++j) {
            buf[0][s][j] = BLOAD2(s, j, 0);
            buf[1][s][j] = BLOAD2(s, j, 1);
        }

    for (int tap = 0; tap < 9; ++tap) {
        const int dy = tap / 3 - 1;
        const int dx = tap - (tap / 3) * 3 - 1;
#pragma unroll
        for (int ci = 0; ci < 2; ++ci) {
            const int kc = tap * 2 + ci;
#pragma unroll
            for (int ih = 0; ih < 2; ++ih) {
                i32x4 af[4];
#pragma unroll
                for (int i4 = 0; i4 < 4; ++i4) {
                    const int i = ih * 4 + i4;
                    const int col = (i & 1) * 16 + lane15 + 1 + dx;
                    const int sp  = ((i >> 1) + 1 + dy) * 34 + col;
                    const int g   = (ci * 4 + q) ^ (col & 7);
                    af[i4] = *(const i32x4*)&img[sp * 128 + g * 16];
                }
#pragma unroll
                for (int s = 0; s < 2; ++s)
#pragma unroll
                    for (int j = 0; j < 2; ++j)
#pragma unroll
                        for (int i4 = 0; i4 < 4; ++i4)
                            acc[ih * 4 + i4][j][s] = __builtin_amdgcn_mfma_i32_16x16x64_i8(
                                af[i4], buf[kc & 1][s][j], acc[ih * 4 + i4][j][s], 0, 0, 0);
            }
            const int kcn = (kc + 2 < 18) ? kc + 2 : kc - 16;
#pragma unroll
            for (int s = 0; s < 2; ++s)
#pragma unroll
                for (int j = 0; j < 2; ++j) buf[kc & 1][s][j] = BLOAD2(s, j, kcn);
        }
    }
#undef BLOAD2

    float offv[2], svf[2];
#pragma unroll
    for (int j = 0; j < 2; ++j) {
        const int c = cb + j * 16 + lane15;
        offv[j] = off[c];
        svf[j]  = scl[c];
    }
#pragma unroll
    for (int i = 0; i < 8; ++i) {
        const int prow = pblk * 128 + i * 16 + q * 4;
#pragma unroll
        for (int j = 0; j < 2; ++j) {
            const int col = cb + j * 16 + lane15;
            f32x4 vv;
#pragma unroll
            for (int rg = 0; rg < 4; ++rg)
                vv[rg] = fmaf((float)acc[i][j][0][rg]
                            + (float)acc[i][j][1][rg] * (1.0f / 254.0f), svf[j], offv[j]);
            *(f32x4*)&out[(size_t)tb * 131072 + (size_t)col * 1024 + prow] = vv;
        }
    }
}

extern "C" void kernel_launch(void* const* d_in, const int* in_sizes, int n_in,
                              void* d_out, int out_size, void* d_ws, size_t ws_size,
                              hipStream_t stream)
{
    const float* x  = (const float*)d_in[0];
    const float* w1 = (const float*)d_in[1];
    const float* g1 = (const float*)d_in[2];
    const float* b1 = (const float*)d_in[3];
    const float* m1 = (const float*)d_in[4];
    const float* v1 = (const float*)d_in[5];
    const float* w2 = (const float*)d_in[6];
    const float* g2 = (const float*)d_in[7];
    const float* b2 = (const float*)d_in[8];
    const float* m2 = (const float*)d_in[9];
    const float* v2 = (const float*)d_in[10];
    float* out = (float*)d_out;

    // ws layout: s1 i8 | s2 i8 | digits | off | scl | cnt | list
    char* ws = (char*)d_ws;
    signed char* s1 = (signed char*)ws;                           //  33,554,432 B
    signed char* s2 = (signed char*)(ws + (size_t)33554432);      //  33,554,432 B
    signed char* wp = (signed char*)(ws + (size_t)67108864);      //     737,280 B
    float*  off  = (float*)(ws + (size_t)67846144);               //       1,024 B
    float*  scl  = (float*)(ws + (size_t)67847168);               //       1,024 B
    int*    cnt  = (int*)  (ws + (size_t)67848192);               //           4 B
    int*    list = (int*)  (ws + (size_t)67848704);               //       16 MB cap

    prep_kernel<<<256, 128, 0, stream>>>(w1, g1, b1, m1, v1, w2, g2, b2, m2, v2,
                                         wp, off, scl, cnt);
    if1_kernel<<<1024, 256, 0, stream>>>(x, s1);
    conv1_if2_kernel<<<512, 256, 0, stream>>>(s1, wp, off, scl, s2, cnt, list);
    redo_kernel<<<2048, 256, 0, stream>>>(s1, w1, g1, b1, m1, v1, cnt, list, s2);
    conv2_kernel<<<2048, 256, 0, stream>>>(s2, wp + 442368, off + 128, scl + 128, out);
}

// Round 4
// 632.181 us; speedup vs baseline: 1.1545x; 1.1545x over previous
//
#include <hip/hip_runtime.h>
#include <hip/hip_bf16.h>

typedef float f32x4 __attribute__((ext_vector_type(4)));
typedef int   i32x4 __attribute__((ext_vector_type(4)));

#define DELTA 5e-5f
#define LIST_CAP 4194304

// ---------------- weight prep: fold BN, per-cout i8 digit decomposition -------
// S = max_k |w*inv| / 127 (rounded to f32). d0=rint(w/S); d1=rint(254r/S);
// d2=rint(64516 r/S) (conv1 only). Layout per conv per split: [kc][cout][kk],
// k=r*128+cin, kc=k>>6, kk=k&63; split stride 147456 B; conv2 at +442368.
// Also zeroes the 2KB zero-buffer used by conv1's global_load_lds OOB lanes.
__global__ void prep_kernel(const float* __restrict__ w1, const float* __restrict__ g1,
                            const float* __restrict__ b1, const float* __restrict__ m1,
                            const float* __restrict__ v1,
                            const float* __restrict__ w2, const float* __restrict__ g2,
                            const float* __restrict__ b2, const float* __restrict__ m2,
                            const float* __restrict__ v2,
                            signed char* __restrict__ wp, float* __restrict__ off,
                            float* __restrict__ scl, int* __restrict__ cnt,
                            signed char* __restrict__ zb)
{
    __shared__ double red[128];
    const int blk  = blockIdx.x;       // 256 blocks = conv*128 + cout
    const int conv = blk >> 7;
    const int cout = blk & 127;
    const int cin  = threadIdx.x;      // 128 threads
    const float* w  = conv ? w2 : w1;
    const float* g  = conv ? g2 : g1;
    const float* bb = conv ? b2 : b1;
    const float* mm = conv ? m2 : m1;
    const float* vr = conv ? v2 : v1;
    if (blk == 0) { int4 z = {0,0,0,0}; *(int4*)(zb + cin * 16) = z; }  // 2KB zeros
    const float invf = g[cout] / sqrtf(vr[cout] + 1e-5f);
    double wv[9];
    double mx = 0.0;
#pragma unroll
    for (int r = 0; r < 9; ++r) {
        wv[r] = (double)w[(size_t)(cout * 128 + cin) * 9 + r] * (double)invf;
        mx = fmax(mx, fabs(wv[r]));
    }
    red[cin] = mx;
    __syncthreads();
    for (int s = 64; s > 0; s >>= 1) {
        if (cin < s) red[cin] = fmax(red[cin], red[cin + s]);
        __syncthreads();
    }
    double S = red[0];
    S = (S > 0.0) ? (double)(float)(S / 127.0) : 1.0;
    const size_t base = conv ? (size_t)442368 : (size_t)0;
#pragma unroll
    for (int r = 0; r < 9; ++r) {
        double x = wv[r];
        const int k = r * 128 + cin;
        const size_t pos = ((size_t)(k >> 6) * 128 + cout) * 64 + (k & 63);
        int d0 = (int)rint(x / S);          x -= (double)d0 * S;
        int d1 = (int)rint(x * 254.0 / S);  x -= (double)d1 * S / 254.0;
        wp[base + pos]          = (signed char)d0;
        wp[base + 147456 + pos] = (signed char)d1;
        if (conv == 0) {
            int d2 = (int)rint(x * 64516.0 / S);
            wp[base + 294912 + pos] = (signed char)d2;
        }
    }
    if (cin == 0) {
        scl[conv * 128 + cout] = (float)S;
        off[conv * 128 + cout] = bb[cout] - mm[cout] * invf;
        if (blk == 0) cnt[0] = 0;          // ws re-poisoned every launch
    }
}

// ---------------- IF neuron #1: x [T,B,C,H,W] f32 -> spikes NHWC i8 -----------
// fp64 membrane: bit-matches an fp64 reference's spike decisions.
__global__ void if1_kernel(const float* __restrict__ x, signed char* __restrict__ s1)
{
    const int blk = blockIdx.x;        // 1024 = B*H
    const int b   = blk >> 5;
    const int h   = blk & 31;
    const int tid = threadIdx.x;
    const int w   = tid & 31;
    const int g   = tid >> 5;          // 8 groups of 16 channels
    double v[16];
#pragma unroll
    for (int i = 0; i < 16; ++i) v[i] = 0.0;
    for (int t = 0; t < 8; ++t) {
        const size_t xbase = ((((size_t)t * 32 + b) * 128 + g * 16) * 32 + h) * 32 + w;
        unsigned wds[4] = {0u, 0u, 0u, 0u};
#pragma unroll
        for (int i = 0; i < 16; ++i) {
            v[i] += (double)x[xbase + (size_t)i * 1024];
            const bool s = (v[i] >= 1.0);
            if (s) { wds[i >> 2] |= 1u << (8 * (i & 3)); v[i] = 0.0; }
        }
        int4 pk; pk.x = wds[0]; pk.y = wds[1]; pk.z = wds[2]; pk.w = wds[3];
        *(int4*)(s1 + (((size_t)(t * 32 + b) * 1024 + h * 32 + w) * 128 + g * 16)) = pk;
    }
}

// ---------------- conv1 (+folded BN) fused with IF#2 --------------------------
// Block = (b, 2-row strip, cout-half): grid 1024. Wave tile 64px x 16 couts so
// acc(48)+v(16)+buf(24) fits ~128 VGPR (round-3 spilled at 230 live / 128 alloc).
// Staging: global_load_lds (no staging VGPRs), double-buffered LDS, source-side
// XOR pre-swizzle; OOB lanes read a zeroed 2KB buffer. s2 is written in
// pixel-quad-major layout [g4=p>>2][cout][p&3]: each thread packs its 4
// consecutive pixels (rg=p&3) into one u32 -> wave store = full 64B sectors.
// Membrane v persists in registers across t; DELTA-flagged sites get exact
// fp64 redo later (digit-combine error ~1e-6 << DELTA).
__global__ __launch_bounds__(256, 2)
void conv1_if2_kernel(const signed char* __restrict__ sin,
                      const signed char* __restrict__ wp,
                      const float* __restrict__ off, const float* __restrict__ scl,
                      const signed char* __restrict__ zb,
                      signed char* __restrict__ s2q,
                      int* __restrict__ cnt, int* __restrict__ list)
{
    __shared__ signed char img[2][4 * 34 * 128];   // 2 x 17408 B
    const int tid   = threadIdx.x;
    const int blk   = blockIdx.x;      // 1024 = b*32 + strip*2 + ch
    const int b     = blk >> 5;
    const int strip = (blk >> 1) & 15; // 2 output rows each
    const int ch    = blk & 1;
    const int wn = tid >> 6;
    const int lane15 = tid & 15;
    const int q  = (tid >> 4) & 3;
    const int cb = ch * 64 + wn * 16;
    const int y0 = strip << 1;

    // per-lane staging source offsets (t-invariant): 1088 units = 136 px x 8 chunks
    // LDS dst is LINEAR (unit*16); XOR swizzle is applied on the SOURCE address.
    int soff[5];
#pragma unroll
    for (int k = 0; k < 5; ++k) {
        const int unit = tid + k * 256;       // < 1088 guaranteed for k<4
        const int sp = unit >> 3, G = unit & 7;
        const int row = sp / 34, col = sp - row * 34;
        const int y = y0 + row - 1, xg = col - 1;
        soff[k] = (y >= 0 && y < 32 && xg >= 0 && xg < 32)
                  ? ((y * 32 + xg) * 128 + ((G ^ (col & 7)) * 16)) : -1;
    }

    const float offv = off[cb + lane15];
    const float svf  = scl[cb + lane15];

#define STAGE1(tsel, dstbuf)                                                          \
    {                                                                                 \
        const signed char* gbase = sin + (size_t)((tsel) * 32 + b) * 131072;          \
        _Pragma("unroll")                                                             \
        for (int k = 0; k < 4; ++k) {                                                 \
            const signed char* src = (soff[k] >= 0) ? (gbase + soff[k])               \
                                                    : (zb + (tid & 63) * 16);         \
            __builtin_amdgcn_global_load_lds(                                         \
                (const __attribute__((address_space(1))) unsigned int*)src,           \
                (__attribute__((address_space(3))) unsigned int*)                     \
                    (&img[dstbuf][0] + (k * 256 + wn * 64) * 16), 16, 0, 0);          \
        }                                                                             \
        if (wn == 0) {  /* units 1024..1087: exactly wave 0, wave-uniform */          \
            const signed char* src = (soff[4] >= 0) ? (gbase + soff[4])               \
                                                    : (zb + (tid & 63) * 16);         \
            __builtin_amdgcn_global_load_lds(                                         \
                (const __attribute__((address_space(1))) unsigned int*)src,           \
                (__attribute__((address_space(3))) unsigned int*)                     \
                    (&img[dstbuf][0] + 1024 * 16), 16, 0, 0);                         \
        }                                                                             \
    }

    STAGE1(0, 0);
    __syncthreads();   // compiler drains vmcnt before barrier -> img[0] ready

    const signed char* wbase = wp + ((size_t)(cb + lane15) * 64 + q * 16);
#define BLOAD1(s, kc) (*(const i32x4*)(wbase + (size_t)((s) * 18 + (kc)) * 8192))

    i32x4 buf[2][3];
#pragma unroll
    for (int s = 0; s < 3; ++s) { buf[0][s] = BLOAD1(s, 0); buf[1][s] = BLOAD1(s, 1); }

    float v[4][4];
#pragma unroll
    for (int i = 0; i < 4; ++i)
#pragma unroll
        for (int rg = 0; rg < 4; ++rg) v[i][rg] = 0.f;
    unsigned fmask = 0;

    for (int t = 0; t < 8; ++t) {
        const int cur = t & 1;
        if (t < 7) STAGE1(t + 1, cur ^ 1);   // async into other buffer

        const signed char* ib = &img[cur][0];
        i32x4 acc[4][3];
#pragma unroll
        for (int i = 0; i < 4; ++i)
#pragma unroll
            for (int s = 0; s < 3; ++s)
#pragma unroll
                for (int rg = 0; rg < 4; ++rg) acc[i][s][rg] = 0;

        for (int tap = 0; tap < 9; ++tap) {
            const int dy = tap / 3 - 1;
            const int dx = tap - (tap / 3) * 3 - 1;
#pragma unroll
            for (int ci = 0; ci < 2; ++ci) {
                const int kc = tap * 2 + ci;
                i32x4 af[4];
#pragma unroll
                for (int i4 = 0; i4 < 4; ++i4) {
                    const int col  = (i4 & 1) * 16 + lane15 + 1 + dx;
                    const int rowl = (i4 >> 1) + 1 + dy;
                    const int g    = (ci * 4 + q) ^ (col & 7);
                    af[i4] = *(const i32x4*)&ib[(rowl * 34 + col) * 128 + g * 16];
                }
#pragma unroll
                for (int s = 0; s < 3; ++s)
#pragma unroll
                    for (int i4 = 0; i4 < 4; ++i4)
                        acc[i4][s] = __builtin_amdgcn_mfma_i32_16x16x64_i8(
                            af[i4], buf[kc & 1][s], acc[i4][s], 0, 0, 0);
                const int kcn = (kc + 2 < 18) ? kc + 2 : kc - 16;   // ring primed for next t
#pragma unroll
                for (int s = 0; s < 3; ++s) buf[kc & 1][s] = BLOAD1(s, kcn);
            }
        }

        // membrane + spike + flag; pack 4 consecutive pixels (rg) into one u32.
        // s2q layout: [(tb*256 + g4)*128 + c]*4 + (p&3), g4 = strip*16 + i4*4 + q.
        const size_t g4base = ((size_t)(t * 32 + b) * 256 + strip * 16);
#pragma unroll
        for (int i4 = 0; i4 < 4; ++i4) {
            unsigned pk = 0;
#pragma unroll
            for (int rg = 0; rg < 4; ++rg) {
                const float yv = fmaf((float)acc[i4][0][rg]
                               + (float)acc[i4][1][rg] * (1.0f / 254.0f)
                               + (float)acc[i4][2][rg] * (1.0f / 64516.0f), svf, offv);
                v[i4][rg] += yv;
                const float d = v[i4][rg] - 1.0f;
                if (fabsf(d) < DELTA) fmask |= 1u << (i4 * 4 + rg);
                if (d >= 0.0f) { pk |= 1u << (8 * rg); v[i4][rg] = 0.f; }
            }
            *(unsigned*)(s2q + ((g4base + i4 * 4 + q) * 128 + cb + lane15) * 4) = pk;
        }

        __syncthreads();   // drains next-t loads; all waves done with img[cur]
    }
#undef BLOAD1
#undef STAGE1

    if (fmask) {
#pragma unroll 1
        for (int k = 0; k < 16; ++k)
            if ((fmask >> k) & 1) {
                const int i4 = k >> 2, rg = k & 3;
                const int p = strip * 64 + i4 * 16 + q * 4 + rg;
                const int pos = atomicAdd(cnt, 1);
                if (pos < LIST_CAP)
                    list[pos] = (b << 17) | (p << 7) | (cb + lane15);
            }
    }
}

// ---------------- IF#2 phase B: fp64 redo from stored s1 spikes ---------------
// s1 holds if1's exact fp64 spike decisions (NHWC, cin-contiguous rows).
// Writes corrected spikes into the pixel-quad-major s2q layout.
__global__ __launch_bounds__(256)
void redo_kernel(const signed char* __restrict__ s1, const float* __restrict__ w1,
                 const float* __restrict__ g1, const float* __restrict__ b1,
                 const float* __restrict__ m1, const float* __restrict__ v1r,
                 const int* __restrict__ cnt, const int* __restrict__ list,
                 signed char* __restrict__ s2q)
{
    __shared__ double red[256][8];   // 16 KB
    const int count = min(cnt[0], LIST_CAP);
    const int tid = threadIdx.x;
    const int cin = tid & 127;
    const int tg  = tid >> 7;
    for (int i = blockIdx.x; i < count; i += gridDim.x) {
        const int pk = list[i];
        const int b = pk >> 17, p = (pk >> 7) & 1023, c = pk & 127;
        const int h = p >> 5, w_ = p & 31;
        double part[8];
#pragma unroll
        for (int t = 0; t < 8; ++t) part[t] = 0.0;
        const int tap0 = tg ? 5 : 0, tap1 = tg ? 9 : 5;
        for (int tap = tap0; tap < tap1; ++tap) {
            const int hh = h + tap / 3 - 1;
            const int ww = w_ + tap - (tap / 3) * 3 - 1;
            if (hh < 0 || hh > 31 || ww < 0 || ww > 31) continue;
            const int pix = hh * 32 + ww;
            const double wv = (double)w1[(size_t)(c * 128 + cin) * 9 + tap];
#pragma unroll
            for (int t = 0; t < 8; ++t)
                if (s1[((size_t)(t * 32 + b) * 1024 + pix) * 128 + cin]) part[t] += wv;
        }
#pragma unroll
        for (int t = 0; t < 8; ++t) red[tid][t] = part[t];
        __syncthreads();
        for (int s = 128; s > 0; s >>= 1) {
            if (tid < s)
#pragma unroll
                for (int t = 0; t < 8; ++t) red[tid][t] += red[tid + s][t];
            __syncthreads();
        }
        if (tid == 0) {
            const double inv  = (double)g1[c] / sqrt((double)v1r[c] + 1e-5);
            const double offc = (double)b1[c] - (double)m1[c] * inv;
            double v = 0.0;
#pragma unroll
            for (int t = 0; t < 8; ++t) {
                v += red[0][t] * inv + offc;
                const bool s = (v >= 1.0);
                s2q[(((size_t)(t * 32 + b) * 256 + (p >> 2)) * 128 + c) * 4 + (p & 3)]
                    = s ? 1 : 0;
                if (s) v = 0.0;
            }
        }
        __syncthreads();   // LDS reused next site
    }
}

// ---------------- conv2 (+folded BN), i8 pipe, NCHW out -----------------------
// Block = (tb, 4-row strip, cout-half): grid 4096. Wave = 128px x 16 couts:
// acc(64)+buf(16) fits ~128 VGPR. Staging transposes the pixel-quad-major s2q
// into pixel-major LDS via v_perm 4x4 byte transpose (12 perms / 16B tile).
// NCHW stores: 4 q-lanes of a col write 64B contiguous -> full sectors.
__global__ __launch_bounds__(256, 2)
void conv2_kernel(const signed char* __restrict__ s2q, const signed char* __restrict__ wp,
                  const float* __restrict__ off, const float* __restrict__ scl,
                  float* __restrict__ out)
{
    __shared__ signed char img[6 * 34 * 128];   // 26,112 B
    const int tid  = threadIdx.x;
    const int blk  = blockIdx.x;     // 4096 = tb*16 + pblk*2 + ch
    const int tb   = blk >> 4;
    const int pblk = (blk >> 1) & 7;
    const int ch   = blk & 1;
    const int wn = tid >> 6;
    const int lane15 = tid & 15;
    const int q  = (tid >> 4) & 3;
    const int cb = ch * 64 + wn * 16;

    // halo columns (col 0 and 33) zero-fill: 6 rows x 2 cols x 128 B
    if (tid < 96) {
        const int rrow = tid >> 4, side = (tid >> 3) & 1, G = tid & 7;
        int4 z = {0, 0, 0, 0};
        *(int4*)&img[(rrow * 34 + side * 33) * 128 + G * 16] = z;
    }
    // main staging: 1536 units = 6 rows x 8 xg4 x 32 c4; each unit = 16 B of
    // s2q (4 couts x 4 pixels) -> 4x4 byte transpose -> 4 u32 pixel-major writes
#pragma unroll
    for (int k = 0; k < 6; ++k) {
        const int unit = tid + k * 256;
        const int rrow = unit >> 8;
        const int xg4  = (unit >> 5) & 7;
        const int c4   = unit & 31;
        const int y    = (pblk << 2) + rrow - 1;
        unsigned o0 = 0, o1 = 0, o2 = 0, o3 = 0;
        if (y >= 0 && y < 32) {
            const uint4 ld = *(const uint4*)(s2q +
                (((size_t)tb * 256 + y * 8 + xg4) * 128 + c4 * 4) * 4);
            unsigned a, bp;
            a  = __builtin_amdgcn_perm(ld.y, ld.x, 0x0400u);
            bp = __builtin_amdgcn_perm(ld.w, ld.z, 0x0400u);
            o0 = __builtin_amdgcn_perm(bp, a, 0x05040100u);
            a  = __builtin_amdgcn_perm(ld.y, ld.x, 0x0501u);
            bp = __builtin_amdgcn_perm(ld.w, ld.z, 0x0501u);
            o1 = __builtin_amdgcn_perm(bp, a, 0x05040100u);
            a  = __builtin_amdgcn_perm(ld.y, ld.x, 0x0602u);
            bp = __builtin_amdgcn_perm(ld.w, ld.z, 0x0602u);
            o2 = __builtin_amdgcn_perm(bp, a, 0x05040100u);
            a  = __builtin_amdgcn_perm(ld.y, ld.x, 0x0703u);
            bp = __builtin_amdgcn_perm(ld.w, ld.z, 0x0703u);
            o3 = __builtin_amdgcn_perm(bp, a, 0x05040100u);
        }
        const int G = c4 >> 2, w4 = (c4 & 3) * 4;
        {
            const int col = xg4 * 4 + 1;
            const int base = (rrow * 34 + col) * 128 + w4;
            *(unsigned*)&img[base +       ((G ^ ( col      & 7)) * 16)] = o0;
            *(unsigned*)&img[base + 128 + ((G ^ ((col + 1) & 7)) * 16)] = o1;
            *(unsigned*)&img[base + 256 + ((G ^ ((col + 2) & 7)) * 16)] = o2;
            *(unsigned*)&img[base + 384 + ((G ^ ((col + 3) & 7)) * 16)] = o3;
        }
    }
    __syncthreads();

    i32x4 acc[8][2];   // [i][split]
#pragma unroll
    for (int i = 0; i < 8; ++i)
#pragma unroll
        for (int s = 0; s < 2; ++s)
#pragma unroll
            for (int rg = 0; rg < 4; ++rg) acc[i][s][rg] = 0;

    const signed char* wbase = wp + ((size_t)(cb + lane15) * 64 + q * 16);
#define BLOAD2(s, kc) (*(const i32x4*)(wbase + (size_t)((s) * 18 + (kc)) * 8192))

    i32x4 buf[2][2];
#pragma unroll
    for (int s = 0; s < 2; ++s) { buf[0][s] = BLOAD2(s, 0); buf[1][s] = BLOAD2(s, 1); }

    for (int tap = 0; tap < 9; ++tap) {
        const int dy = tap / 3 - 1;
        const int dx = tap - (tap / 3) * 3 - 1;
#pragma unroll
        for (int ci = 0; ci < 2; ++ci) {
            const int kc = tap * 2 + ci;
#pragma unroll
            for (int ih = 0; ih < 2; ++ih) {
                i32x4 af[4];
#pragma unroll
                for (int i4 = 0; i4 < 4; ++i4) {
                    const int i = ih * 4 + i4;
                    const int col = (i & 1) * 16 + lane15 + 1 + dx;
                    const int sp  = ((i >> 1) + 1 + dy) * 34 + col;
                    const int g   = (ci * 4 + q) ^ (col & 7);
                    af[i4] = *(const i32x4*)&img[sp * 128 + g * 16];
                }
#pragma unroll
                for (int s = 0; s < 2; ++s)
#pragma unroll
                    for (int i4 = 0; i4 < 4; ++i4)
                        acc[ih * 4 + i4][s] = __builtin_amdgcn_mfma_i32_16x16x64_i8(
                            af[i4], buf[kc & 1][s], acc[ih * 4 + i4][s], 0, 0, 0);
            }
            const int kcn = (kc + 2 < 18) ? kc + 2 : kc - 16;
#pragma unroll
            for (int s = 0; s < 2; ++s) buf[kc & 1][s] = BLOAD2(s, kcn);
        }
    }
#undef BLOAD2

    const int col = cb + lane15;
    const float offv = off[col];
    const float svf  = scl[col];
#pragma unroll
    for (int i = 0; i < 8; ++i) {
        const int prow = pblk * 128 + i * 16 + q * 4;
        f32x4 vv;
#pragma unroll
        for (int rg = 0; rg < 4; ++rg)
            vv[rg] = fmaf((float)acc[i][0][rg]
                        + (float)acc[i][1][rg] * (1.0f / 254.0f), svf, offv);
        *(f32x4*)&out[(size_t)tb * 131072 + (size_t)col * 1024 + prow] = vv;
    }
}

extern "C" void kernel_launch(void* const* d_in, const int* in_sizes, int n_in,
                              void* d_out, int out_size, void* d_ws, size_t ws_size,
                              hipStream_t stream)
{
    const float* x  = (const float*)d_in[0];
    const float* w1 = (const float*)d_in[1];
    const float* g1 = (const float*)d_in[2];
    const float* b1 = (const float*)d_in[3];
    const float* m1 = (const float*)d_in[4];
    const float* v1 = (const float*)d_in[5];
    const float* w2 = (const float*)d_in[6];
    const float* g2 = (const float*)d_in[7];
    const float* b2 = (const float*)d_in[8];
    const float* m2 = (const float*)d_in[9];
    const float* v2 = (const float*)d_in[10];
    float* out = (float*)d_out;

    // ws layout: s1 i8 NHWC | s2 i8 quad-major | digits | off | scl | cnt | list | zb
    char* ws = (char*)d_ws;
    signed char* s1  = (signed char*)ws;                          //  33,554,432 B
    signed char* s2q = (signed char*)(ws + (size_t)33554432);     //  33,554,432 B
    signed char* wp  = (signed char*)(ws + (size_t)67108864);     //     737,280 B
    float*  off  = (float*)(ws + (size_t)67846144);               //       1,024 B
    float*  scl  = (float*)(ws + (size_t)67847168);               //       1,024 B
    int*    cnt  = (int*)  (ws + (size_t)67848192);               //           4 B
    int*    list = (int*)  (ws + (size_t)67848704);               //       16 MB cap
    signed char* zb = (signed char*)(ws + (size_t)84625920);      //       2,048 B

    prep_kernel<<<256, 128, 0, stream>>>(w1, g1, b1, m1, v1, w2, g2, b2, m2, v2,
                                         wp, off, scl, cnt, zb);
    if1_kernel<<<1024, 256, 0, stream>>>(x, s1);
    conv1_if2_kernel<<<1024, 256, 0, stream>>>(s1, wp, off, scl, zb, s2q, cnt, list);
    redo_kernel<<<2048, 256, 0, stream>>>(s1, w1, g1, b1, m1, v1, cnt, list, s2q);
    conv2_kernel<<<4096, 256, 0, stream>>>(s2q, wp + 442368, off + 128, scl + 128, out);
}

// Round 5
// 479.852 us; speedup vs baseline: 1.5210x; 1.3174x over previous
//
#include <hip/hip_runtime.h>
#include <hip/hip_bf16.h>

typedef float f32x4 __attribute__((ext_vector_type(4)));
typedef int   i32x4 __attribute__((ext_vector_type(4)));

#define DELTA 5e-5f
#define LIST_CAP 4194304

// ---------------- weight prep: fold BN, per-cout i8 digit decomposition -------
// S = max_k |w*inv| / 127 (rounded to f32). d0=rint(w/S); d1=rint(254r/S);
// d2=rint(64516 r/S) (conv1 only). Layout per conv per split: [kc][cout][kk],
// k=r*128+cin, kc=k>>6, kk=k&63; split stride 147456 B; conv2 at +442368.
// Also zeroes the 2KB zero-buffer used by conv1's global_load_lds OOB lanes.
__global__ void prep_kernel(const float* __restrict__ w1, const float* __restrict__ g1,
                            const float* __restrict__ b1, const float* __restrict__ m1,
                            const float* __restrict__ v1,
                            const float* __restrict__ w2, const float* __restrict__ g2,
                            const float* __restrict__ b2, const float* __restrict__ m2,
                            const float* __restrict__ v2,
                            signed char* __restrict__ wp, float* __restrict__ off,
                            float* __restrict__ scl, int* __restrict__ cnt,
                            signed char* __restrict__ zb)
{
    __shared__ double red[128];
    const int blk  = blockIdx.x;       // 256 blocks = conv*128 + cout
    const int conv = blk >> 7;
    const int cout = blk & 127;
    const int cin  = threadIdx.x;      // 128 threads
    const float* w  = conv ? w2 : w1;
    const float* g  = conv ? g2 : g1;
    const float* bb = conv ? b2 : b1;
    const float* mm = conv ? m2 : m1;
    const float* vr = conv ? v2 : v1;
    if (blk == 0) { int4 z = {0,0,0,0}; *(int4*)(zb + cin * 16) = z; }  // 2KB zeros
    const float invf = g[cout] / sqrtf(vr[cout] + 1e-5f);
    double wv[9];
    double mx = 0.0;
#pragma unroll
    for (int r = 0; r < 9; ++r) {
        wv[r] = (double)w[(size_t)(cout * 128 + cin) * 9 + r] * (double)invf;
        mx = fmax(mx, fabs(wv[r]));
    }
    red[cin] = mx;
    __syncthreads();
    for (int s = 64; s > 0; s >>= 1) {
        if (cin < s) red[cin] = fmax(red[cin], red[cin + s]);
        __syncthreads();
    }
    double S = red[0];
    S = (S > 0.0) ? (double)(float)(S / 127.0) : 1.0;
    const size_t base = conv ? (size_t)442368 : (size_t)0;
#pragma unroll
    for (int r = 0; r < 9; ++r) {
        double x = wv[r];
        const int k = r * 128 + cin;
        const size_t pos = ((size_t)(k >> 6) * 128 + cout) * 64 + (k & 63);
        int d0 = (int)rint(x / S);          x -= (double)d0 * S;
        int d1 = (int)rint(x * 254.0 / S);  x -= (double)d1 * S / 254.0;
        wp[base + pos]          = (signed char)d0;
        wp[base + 147456 + pos] = (signed char)d1;
        if (conv == 0) {
            int d2 = (int)rint(x * 64516.0 / S);
            wp[base + 294912 + pos] = (signed char)d2;
        }
    }
    if (cin == 0) {
        scl[conv * 128 + cout] = (float)S;
        off[conv * 128 + cout] = bb[cout] - mm[cout] * invf;
        if (blk == 0) cnt[0] = 0;          // ws re-poisoned every launch
    }
}

// ---------------- IF neuron #1: x [T,B,C,H,W] f32 -> spikes NHWC i8 -----------
// fp64 membrane: bit-matches an fp64 reference's spike decisions.
__global__ void if1_kernel(const float* __restrict__ x, signed char* __restrict__ s1)
{
    const int blk = blockIdx.x;        // 1024 = B*H
    const int b   = blk >> 5;
    const int h   = blk & 31;
    const int tid = threadIdx.x;
    const int w   = tid & 31;
    const int g   = tid >> 5;          // 8 groups of 16 channels
    double v[16];
#pragma unroll
    for (int i = 0; i < 16; ++i) v[i] = 0.0;
    for (int t = 0; t < 8; ++t) {
        const size_t xbase = ((((size_t)t * 32 + b) * 128 + g * 16) * 32 + h) * 32 + w;
        unsigned wds[4] = {0u, 0u, 0u, 0u};
#pragma unroll
        for (int i = 0; i < 16; ++i) {
            v[i] += (double)x[xbase + (size_t)i * 1024];
            const bool s = (v[i] >= 1.0);
            if (s) { wds[i >> 2] |= 1u << (8 * (i & 3)); v[i] = 0.0; }
        }
        int4 pk; pk.x = wds[0]; pk.y = wds[1]; pk.z = wds[2]; pk.w = wds[3];
        *(int4*)(s1 + (((size_t)(t * 32 + b) * 1024 + h * 32 + w) * 128 + g * 16)) = pk;
    }
}

// ---------------- conv1 (+folded BN) fused with IF#2, LDS-resident weights ----
// Block = (cgrp, b, 2-row strip): grid 2048, cgrp in HIGH bits (XCD-sharing of
// s1 among cout-group twins). Per block: stage the 32-cout weight slice
// (3 splits x 18 kc x 2048 B = 110.6 KB, contiguous runs in wp) into LDS ONCE,
// then 8 t-iterations read weights from LDS -> kills the per-t 1.77 GB weight
// ring that round-3/4 counters showed missing L2 (~700 MB/launch HBM fetch).
// Weight LDS uses a bits7:8->4:5 XOR involution (pre-swizzled source, swizzled
// read) for bank uniformity. Wave tile 32px x 16 couts: acc 24 + v 8 VGPRs,
// no spill risk. img double-buffered via global_load_lds (round-4 pattern).
__global__ __launch_bounds__(256, 1)
void conv1_if2_kernel(const signed char* __restrict__ sin,
                      const signed char* __restrict__ wp,
                      const float* __restrict__ off, const float* __restrict__ scl,
                      const signed char* __restrict__ zb,
                      signed char* __restrict__ s2q,
                      int* __restrict__ cnt, int* __restrict__ list)
{
    __shared__ signed char lds[110592 + 2 * 17408];   // 145,408 B
    signed char* wlds = lds;
    signed char* img0 = lds + 110592;
    signed char* img1 = lds + 110592 + 17408;
    const int tid   = threadIdx.x;
    const int blk   = blockIdx.x;      // 2048 = cgrp*512 + b*16 + strip
    const int cgrp  = blk >> 9;
    const int bs    = blk & 511;
    const int b     = bs >> 4;
    const int strip = bs & 15;         // 2 output rows each
    const int wn = tid >> 6;
    const int lane15 = tid & 15;
    const int q   = (tid >> 4) & 3;
    const int r_w = wn >> 1;           // output row within strip (0/1)
    const int chf = wn & 1;            // cout 16-half within block's 32
    const int cout = cgrp * 32 + chf * 16 + lane15;
    const int y0 = strip << 1;

    // ---- stage weights: 6912 x 16B units = 27 per thread, linear LDS dest ----
#pragma unroll
    for (int k = 0; k < 27; ++k) {
        const int u   = tid + k * 256;
        const int sk  = u >> 7;              // (split*18+kc)
        const int a   = (u & 127) * 16;      // within-slab dest byte
        const int asw = a ^ (((a >> 7) & 3) << 4);   // involution on bits 4-5
        const signed char* src = wp + sk * 8192 + cgrp * 2048 + asw;
        __builtin_amdgcn_global_load_lds(
            (const __attribute__((address_space(1))) unsigned int*)src,
            (__attribute__((address_space(3))) unsigned int*)(wlds + u * 16), 16, 0, 0);
    }

    // per-lane img staging source offsets (t-invariant): 1088 units = 136px x 8
    int soff[5];
#pragma unroll
    for (int k = 0; k < 5; ++k) {
        const int unit = tid + k * 256;
        const int sp = unit >> 3, G = unit & 7;
        const int row = sp / 34, col = sp - row * 34;
        const int y = y0 + row - 1, xg = col - 1;
        soff[k] = (y >= 0 && y < 32 && xg >= 0 && xg < 32)
                  ? ((y * 32 + xg) * 128 + ((G ^ (col & 7)) * 16)) : -1;
    }

    const float offv = off[cout];
    const float svf  = scl[cout];

#define STAGE1(tsel, dst)                                                             \
    {                                                                                 \
        const signed char* gbase = sin + (size_t)((tsel) * 32 + b) * 131072;          \
        _Pragma("unroll")                                                             \
        for (int k = 0; k < 4; ++k) {                                                 \
            const signed char* src = (soff[k] >= 0) ? (gbase + soff[k])               \
                                                    : (zb + (tid & 63) * 16);         \
            __builtin_amdgcn_global_load_lds(                                         \
                (const __attribute__((address_space(1))) unsigned int*)src,           \
                (__attribute__((address_space(3))) unsigned int*)                     \
                    ((dst) + (k * 256 + wn * 64) * 16), 16, 0, 0);                    \
        }                                                                             \
        if (wn == 0) {  /* units 1024..1087: exactly wave 0, wave-uniform */          \
            const signed char* src = (soff[4] >= 0) ? (gbase + soff[4])               \
                                                    : (zb + (tid & 63) * 16);         \
            __builtin_amdgcn_global_load_lds(                                         \
                (const __attribute__((address_space(1))) unsigned int*)src,           \
                (__attribute__((address_space(3))) unsigned int*)                     \
                    ((dst) + 1024 * 16), 16, 0, 0);                                   \
        }                                                                             \
    }

    STAGE1(0, img0);
    __syncthreads();   // drains all global_load_lds: weights + img[0] ready

    // swizzled per-lane weight read offset within each 2048-B (s,kc) slab
    int aw = (chf * 16 + lane15) * 64 + q * 16;
    aw ^= ((aw >> 7) & 3) << 4;

    float v[2][4];
#pragma unroll
    for (int i = 0; i < 2; ++i)
#pragma unroll
        for (int rg = 0; rg < 4; ++rg) v[i][rg] = 0.f;
    unsigned fmask = 0;

    for (int t = 0; t < 8; ++t) {
        const signed char* ib = (t & 1) ? img1 : img0;
        if (t < 7) { if (t & 1) STAGE1(t + 1, img0) else STAGE1(t + 1, img1) }

        i32x4 acc[2][3];
#pragma unroll
        for (int i = 0; i < 2; ++i)
#pragma unroll
            for (int s = 0; s < 3; ++s)
#pragma unroll
                for (int rg = 0; rg < 4; ++rg) acc[i][s][rg] = 0;

#pragma unroll
        for (int tap = 0; tap < 9; ++tap) {
            const int dy = tap / 3 - 1;
            const int dx = tap - (tap / 3) * 3 - 1;
            const int rowl = r_w + 1 + dy;
#pragma unroll
            for (int ci = 0; ci < 2; ++ci) {
                const int kc = tap * 2 + ci;
                i32x4 af[2];
#pragma unroll
                for (int i2 = 0; i2 < 2; ++i2) {
                    const int col = i2 * 16 + lane15 + 1 + dx;
                    const int g   = (ci * 4 + q) ^ (col & 7);
                    af[i2] = *(const i32x4*)&ib[(rowl * 34 + col) * 128 + g * 16];
                }
#pragma unroll
                for (int s = 0; s < 3; ++s) {
                    const i32x4 wb = *(const i32x4*)&wlds[(s * 18 + kc) * 2048 + aw];
#pragma unroll
                    for (int i2 = 0; i2 < 2; ++i2)
                        acc[i2][s] = __builtin_amdgcn_mfma_i32_16x16x64_i8(
                            af[i2], wb, acc[i2][s], 0, 0, 0);
                }
            }
        }

        // membrane + spike + flag; pack 4 consecutive pixels into one u32.
        // C/D map: col=lane&15 (cout), row=q*4+rg (pixel within 16-px group).
        const size_t g4base = ((size_t)(t * 32 + b) * 256 + (strip * 2 + r_w) * 8);
#pragma unroll
        for (int i2 = 0; i2 < 2; ++i2) {
            unsigned pk = 0;
#pragma unroll
            for (int rg = 0; rg < 4; ++rg) {
                const float yv = fmaf((float)acc[i2][0][rg]
                               + (float)acc[i2][1][rg] * (1.0f / 254.0f)
                               + (float)acc[i2][2][rg] * (1.0f / 64516.0f), svf, offv);
                v[i2][rg] += yv;
                const float d = v[i2][rg] - 1.0f;
                if (fabsf(d) < DELTA) fmask |= 1u << (i2 * 4 + rg);
                if (d >= 0.0f) { pk |= 1u << (8 * rg); v[i2][rg] = 0.f; }
            }
            *(unsigned*)(s2q + ((g4base + i2 * 4 + q) * 128 + cout) * 4) = pk;
        }

        __syncthreads();   // next-t img loads drained; all waves done with ib
    }
#undef STAGE1

    if (fmask) {
#pragma unroll 1
        for (int k = 0; k < 8; ++k)
            if ((fmask >> k) & 1) {
                const int i2 = k >> 2, rg = k & 3;
                const int p = (strip * 2 + r_w) * 32 + i2 * 16 + q * 4 + rg;
                const int pos = atomicAdd(cnt, 1);
                if (pos < LIST_CAP)
                    list[pos] = (b << 17) | (p << 7) | cout;
            }
    }
}

// ---------------- IF#2 phase B: fp64 redo from stored s1 spikes ---------------
// s1 holds if1's exact fp64 spike decisions (NHWC, cin-contiguous rows).
// Writes corrected spikes into the pixel-quad-major s2q layout.
__global__ __launch_bounds__(256)
void redo_kernel(const signed char* __restrict__ s1, const float* __restrict__ w1,
                 const float* __restrict__ g1, const float* __restrict__ b1,
                 const float* __restrict__ m1, const float* __restrict__ v1r,
                 const int* __restrict__ cnt, const int* __restrict__ list,
                 signed char* __restrict__ s2q)
{
    __shared__ double red[256][8];   // 16 KB
    const int count = min(cnt[0], LIST_CAP);
    const int tid = threadIdx.x;
    const int cin = tid & 127;
    const int tg  = tid >> 7;
    for (int i = blockIdx.x; i < count; i += gridDim.x) {
        const int pk = list[i];
        const int b = pk >> 17, p = (pk >> 7) & 1023, c = pk & 127;
        const int h = p >> 5, w_ = p & 31;
        double part[8];
#pragma unroll
        for (int t = 0; t < 8; ++t) part[t] = 0.0;
        const int tap0 = tg ? 5 : 0, tap1 = tg ? 9 : 5;
        for (int tap = tap0; tap < tap1; ++tap) {
            const int hh = h + tap / 3 - 1;
            const int ww = w_ + tap - (tap / 3) * 3 - 1;
            if (hh < 0 || hh > 31 || ww < 0 || ww > 31) continue;
            const int pix = hh * 32 + ww;
            const double wv = (double)w1[(size_t)(c * 128 + cin) * 9 + tap];
#pragma unroll
            for (int t = 0; t < 8; ++t)
                if (s1[((size_t)(t * 32 + b) * 1024 + pix) * 128 + cin]) part[t] += wv;
        }
#pragma unroll
        for (int t = 0; t < 8; ++t) red[tid][t] = part[t];
        __syncthreads();
        for (int s = 128; s > 0; s >>= 1) {
            if (tid < s)
#pragma unroll
                for (int t = 0; t < 8; ++t) red[tid][t] += red[tid + s][t];
            __syncthreads();
        }
        if (tid == 0) {
            const double inv  = (double)g1[c] / sqrt((double)v1r[c] + 1e-5);
            const double offc = (double)b1[c] - (double)m1[c] * inv;
            double v = 0.0;
#pragma unroll
            for (int t = 0; t < 8; ++t) {
                v += red[0][t] * inv + offc;
                const bool s = (v >= 1.0);
                s2q[(((size_t)(t * 32 + b) * 256 + (p >> 2)) * 128 + c) * 4 + (p & 3)]
                    = s ? 1 : 0;
                if (s) v = 0.0;
            }
        }
        __syncthreads();   // LDS reused next site
    }
}

// ---------------- conv2 (+folded BN), i8 pipe, NCHW out -----------------------
// Block = (tb, 4-row strip, cout-half): grid 4096 (no t-loop: weight ring runs
// once per block, round-1 regime where L2 served it at >94%). Staging
// transposes pixel-quad-major s2q into pixel-major LDS via v_perm byte
// transpose. NCHW stores: 4 q-lanes of a col write 64B contiguous sectors.
__global__ __launch_bounds__(256, 2)
void conv2_kernel(const signed char* __restrict__ s2q, const signed char* __restrict__ wp,
                  const float* __restrict__ off, const float* __restrict__ scl,
                  float* __restrict__ out)
{
    __shared__ signed char img[6 * 34 * 128];   // 26,112 B
    const int tid  = threadIdx.x;
    const int blk  = blockIdx.x;     // 4096 = tb*16 + pblk*2 + ch
    const int tb   = blk >> 4;
    const int pblk = (blk >> 1) & 7;
    const int ch   = blk & 1;
    const int wn = tid >> 6;
    const int lane15 = tid & 15;
    const int q  = (tid >> 4) & 3;
    const int cb = ch * 64 + wn * 16;

    // halo columns (col 0 and 33) zero-fill: 6 rows x 2 cols x 128 B
    if (tid < 96) {
        const int rrow = tid >> 4, side = (tid >> 3) & 1, G = tid & 7;
        int4 z = {0, 0, 0, 0};
        *(int4*)&img[(rrow * 34 + side * 33) * 128 + G * 16] = z;
    }
    // main staging: 1536 units = 6 rows x 8 xg4 x 32 c4; each unit = 16 B of
    // s2q (4 couts x 4 pixels) -> 4x4 byte transpose -> 4 u32 pixel-major writes
#pragma unroll
    for (int k = 0; k < 6; ++k) {
        const int unit = tid + k * 256;
        const int rrow = unit >> 8;
        const int xg4  = (unit >> 5) & 7;
        const int c4   = unit & 31;
        const int y    = (pblk << 2) + rrow - 1;
        unsigned o0 = 0, o1 = 0, o2 = 0, o3 = 0;
        if (y >= 0 && y < 32) {
            const uint4 ld = *(const uint4*)(s2q +
                (((size_t)tb * 256 + y * 8 + xg4) * 128 + c4 * 4) * 4);
            unsigned a, bp;
            a  = __builtin_amdgcn_perm(ld.y, ld.x, 0x0400u);
            bp = __builtin_amdgcn_perm(ld.w, ld.z, 0x0400u);
            o0 = __builtin_amdgcn_perm(bp, a, 0x05040100u);
            a  = __builtin_amdgcn_perm(ld.y, ld.x, 0x0501u);
            bp = __builtin_amdgcn_perm(ld.w, ld.z, 0x0501u);
            o1 = __builtin_amdgcn_perm(bp, a, 0x05040100u);
            a  = __builtin_amdgcn_perm(ld.y, ld.x, 0x0602u);
            bp = __builtin_amdgcn_perm(ld.w, ld.z, 0x0602u);
            o2 = __builtin_amdgcn_perm(bp, a, 0x05040100u);
            a  = __builtin_amdgcn_perm(ld.y, ld.x, 0x0703u);
            bp = __builtin_amdgcn_perm(ld.w, ld.z, 0x0703u);
            o3 = __builtin_amdgcn_perm(bp, a, 0x05040100u);
        }
        const int G = c4 >> 2, w4 = (c4 & 3) * 4;
        {
            const int col = xg4 * 4 + 1;
            const int base = (rrow * 34 + col) * 128 + w4;
            *(unsigned*)&img[base +       ((G ^ ( col      & 7)) * 16)] = o0;
            *(unsigned*)&img[base + 128 + ((G ^ ((col + 1) & 7)) * 16)] = o1;
            *(unsigned*)&img[base + 256 + ((G ^ ((col + 2) & 7)) * 16)] = o2;
            *(unsigned*)&img[base + 384 + ((G ^ ((col + 3) & 7)) * 16)] = o3;
        }
    }
    __syncthreads();

    i32x4 acc[8][2];   // [i][split]
#pragma unroll
    for (int i = 0; i < 8; ++i)
#pragma unroll
        for (int s = 0; s < 2; ++s)
#pragma unroll
            for (int rg = 0; rg < 4; ++rg) acc[i][s][rg] = 0;

    const signed char* wbase = wp + ((size_t)(cb + lane15) * 64 + q * 16);
#define BLOAD2(s, kc) (*(const i32x4*)(wbase + (size_t)((s) * 18 + (kc)) * 8192))

    i32x4 buf[2][2];
#pragma unroll
    for (int s = 0; s < 2; ++s) { buf[0][s] = BLOAD2(s, 0); buf[1][s] = BLOAD2(s, 1); }

    for (int tap = 0; tap < 9; ++tap) {
        const int dy = tap / 3 - 1;
        const int dx = tap - (tap / 3) * 3 - 1;
#pragma unroll
        for (int ci = 0; ci < 2; ++ci) {
            const int kc = tap * 2 + ci;
#pragma unroll
            for (int ih = 0; ih < 2; ++ih) {
                i32x4 af[4];
#pragma unroll
                for (int i4 = 0; i4 < 4; ++i4) {
                    const int i = ih * 4 + i4;
                    const int col = (i & 1) * 16 + lane15 + 1 + dx;
                    const int sp  = ((i >> 1) + 1 + dy) * 34 + col;
                    const int g   = (ci * 4 + q) ^ (col & 7);
                    af[i4] = *(const i32x4*)&img[sp * 128 + g * 16];
                }
#pragma unroll
                for (int s = 0; s < 2; ++s)
#pragma unroll
                    for (int i4 = 0; i4 < 4; ++i4)
                        acc[ih * 4 + i4][s] = __builtin_amdgcn_mfma_i32_16x16x64_i8(
                            af[i4], buf[kc & 1][s], acc[ih * 4 + i4][s], 0, 0, 0);
            }
            const int kcn = (kc + 2 < 18) ? kc + 2 : kc - 16;
#pragma unroll
            for (int s = 0; s < 2; ++s) buf[kc & 1][s] = BLOAD2(s, kcn);
        }
    }
#undef BLOAD2

    const int col = cb + lane15;
    const float offv = off[col];
    const float svf  = scl[col];
#pragma unroll
    for (int i = 0; i < 8; ++i) {
        const int prow = pblk * 128 + i * 16 + q * 4;
        f32x4 vv;
#pragma unroll
        for (int rg = 0; rg < 4; ++rg)
            vv[rg] = fmaf((float)acc[i][0][rg]
                        + (float)acc[i][1][rg] * (1.0f / 254.0f), svf, offv);
        *(f32x4*)&out[(size_t)tb * 131072 + (size_t)col * 1024 + prow] = vv;
    }
}

extern "C" void kernel_launch(void* const* d_in, const int* in_sizes, int n_in,
                              void* d_out, int out_size, void* d_ws, size_t ws_size,
                              hipStream_t stream)
{
    const float* x  = (const float*)d_in[0];
    const float* w1 = (const float*)d_in[1];
    const float* g1 = (const float*)d_in[2];
    const float* b1 = (const float*)d_in[3];
    const float* m1 = (const float*)d_in[4];
    const float* v1 = (const float*)d_in[5];
    const float* w2 = (const float*)d_in[6];
    const float* g2 = (const float*)d_in[7];
    const float* b2 = (const float*)d_in[8];
    const float* m2 = (const float*)d_in[9];
    const float* v2 = (const float*)d_in[10];
    float* out = (float*)d_out;

    // ws layout: s1 i8 NHWC | s2 i8 quad-major | digits | off | scl | cnt | list | zb
    char* ws = (char*)d_ws;
    signed char* s1  = (signed char*)ws;                          //  33,554,432 B
    signed char* s2q = (signed char*)(ws + (size_t)33554432);     //  33,554,432 B
    signed char* wp  = (signed char*)(ws + (size_t)67108864);     //     737,280 B
    float*  off  = (float*)(ws + (size_t)67846144);               //       1,024 B
    float*  scl  = (float*)(ws + (size_t)67847168);               //       1,024 B
    int*    cnt  = (int*)  (ws + (size_t)67848192);               //           4 B
    int*    list = (int*)  (ws + (size_t)67848704);               //       16 MB cap
    signed char* zb = (signed char*)(ws + (size_t)84625920);      //       2,048 B

    prep_kernel<<<256, 128, 0, stream>>>(w1, g1, b1, m1, v1, w2, g2, b2, m2, v2,
                                         wp, off, scl, cnt, zb);
    if1_kernel<<<1024, 256, 0, stream>>>(x, s1);
    conv1_if2_kernel<<<2048, 256, 0, stream>>>(s1, wp, off, scl, zb, s2q, cnt, list);
    redo_kernel<<<2048, 256, 0, stream>>>(s1, w1, g1, b1, m1, v1, cnt, list, s2q);
    conv2_kernel<<<4096, 256, 0, stream>>>(s2q, wp + 442368, off + 128, scl + 128, out);
}